// Round 9
// baseline (226.539 us; speedup 1.0000x reference)
//
#include <hip/hip_runtime.h>

#define DIM 512
#define WAVE 64
#define WPB 4
#define RPW 2                         // rows per wave, full 64-lane rows (ILP)
#define BLOCK (WAVE * WPB)
#define ROWS_PER_BLOCK (WPB * RPW)    // 8

typedef float vfloat4 __attribute__((ext_vector_type(4)));

// ---- non-rematerializable 16B load (r8 technique): asm def must stay in VGPRs
__device__ __forceinline__ vfloat4 ga_load16(const float* p) {
    vfloat4 r;
    asm volatile("global_load_dwordx4 %0, %1, off" : "=v"(r) : "v"(p));
    return r;
}

// ---- DS-free 64-lane butterflies (r4: correct, ~10 VALU, no LDS) -----------
#define DPPF(x, ctrl) __int_as_float(__builtin_amdgcn_update_dpp( \
    __float_as_int(x), __float_as_int(x), (ctrl), 0xf, 0xf, false))

__device__ __forceinline__ float red16_sum(float x) {
    x += DPPF(x, 0xB1);   // quad_perm xor1
    x += DPPF(x, 0x4E);   // quad_perm xor2
    x += DPPF(x, 0x124);  // row_ror:4
    x += DPPF(x, 0x128);  // row_ror:8
    return x;
}
__device__ __forceinline__ float red16_max(float x) {
    x = fmaxf(x, DPPF(x, 0xB1));
    x = fmaxf(x, DPPF(x, 0x4E));
    x = fmaxf(x, DPPF(x, 0x124));
    x = fmaxf(x, DPPF(x, 0x128));
    return x;
}
__device__ __forceinline__ float xswap16_sum(float x) {
    float t = x, u = x;
    asm("" : "+v"(u));
    asm("v_permlane16_swap_b32 %0, %1" : "+v"(t), "+v"(u));
    return t + u;
}
__device__ __forceinline__ float xswap32_sum(float x) {
    float t = x, u = x;
    asm("" : "+v"(u));
    asm("v_permlane32_swap_b32 %0, %1" : "+v"(t), "+v"(u));
    return t + u;
}
__device__ __forceinline__ float xswap16_max(float x) {
    float t = x, u = x;
    asm("" : "+v"(u));
    asm("v_permlane16_swap_b32 %0, %1" : "+v"(t), "+v"(u));
    return fmaxf(t, u);
}
__device__ __forceinline__ float xswap32_max(float x) {
    float t = x, u = x;
    asm("" : "+v"(u));
    asm("v_permlane32_swap_b32 %0, %1" : "+v"(t), "+v"(u));
    return fmaxf(t, u);
}
__device__ __forceinline__ float allred_sum(float x) {
    return xswap32_sum(xswap16_sum(red16_sum(x)));
}
__device__ __forceinline__ float allred_max(float x) {
    return xswap32_max(xswap16_max(red16_max(x)));
}

__global__ __launch_bounds__(BLOCK) void sparsemax_kernel(
    const float* __restrict__ x, float* __restrict__ out, int batch) {
    // Diagnosis (r0-r8): per-SIMD row throughput == single-wave serial latency
    // (~2500 cyc/row) with VALUBusy ~30% -> resident waves don't overlap each
    // other's dependency chains. Fix: TWO independent full-width rows per wave,
    // chains interleaved in one instruction stream (true ILP). Residency
    // guaranteed by asm loads (r8). Joint iteration is exact: a converged
    // row's tau recomputes to itself bitwise (same set -> same sum order).
    const int lane = threadIdx.x & 63;
    const int row0 = (blockIdx.x * WPB + (threadIdx.x >> 6)) * RPW;
    if (row0 >= batch) return;

    const float* xr0 = x + (size_t)row0 * DIM;
    const float* xr1 = xr0 + DIM;
    vfloat4 a0 = ga_load16(xr0 + 4 * lane);
    vfloat4 b0 = ga_load16(xr0 + 4 * lane + 256);
    vfloat4 a1 = ga_load16(xr1 + 4 * lane);
    vfloat4 b1 = ga_load16(xr1 + 4 * lane + 256);
    asm volatile("s_waitcnt vmcnt(0)"
                 : "+v"(a0), "+v"(b0), "+v"(a1), "+v"(b1) :: "memory");

    float z0[8] = {a0.x, a0.y, a0.z, a0.w, b0.x, b0.y, b0.z, b0.w};
    float z1[8] = {a1.x, a1.y, a1.z, a1.w, b1.x, b1.y, b1.z, b1.w};

    // ---- tau0 = max - 1, two interleaved reduce chains
    float m0 = fmaxf(fmaxf(fmaxf(z0[0], z0[1]), fmaxf(z0[2], z0[3])),
                     fmaxf(fmaxf(z0[4], z0[5]), fmaxf(z0[6], z0[7])));
    float m1 = fmaxf(fmaxf(fmaxf(z1[0], z1[1]), fmaxf(z1[2], z1[3])),
                     fmaxf(fmaxf(z1[4], z1[5]), fmaxf(z1[6], z1[7])));
    m0 = allred_max(m0);
    m1 = allred_max(m1);
    float tau0 = m0 - 1.0f;
    float tau1 = m1 - 1.0f;

    // ---- joint Michelot fixed point on both rows (chains independent -> ILP)
    int kp0 = -1, kp1 = -1;
    for (int it = 0; it < 32; ++it) {
        float S0 = 0.f, S1 = 0.f;
        int   K0 = 0,   K1 = 0;
#pragma unroll
        for (int j = 0; j < 8; ++j) {
            const bool in0 = z0[j] > tau0;
            const bool in1 = z1[j] > tau1;
            S0 += in0 ? z0[j] : 0.f;
            S1 += in1 ? z1[j] : 0.f;
            K0 += (int)__popcll(__ballot(in0));
            K1 += (int)__popcll(__ballot(in1));
        }
        S0 = allred_sum(S0);
        S1 = allred_sum(S1);
        if (K0 == kp0 && K1 == kp1) break;  // wave-uniform
        kp0 = K0; kp1 = K1;
        tau0 = (S0 - 1.0f) * __builtin_amdgcn_rcpf((float)K0);  // K >= 1
        tau1 = (S1 - 1.0f) * __builtin_amdgcn_rcpf((float)K1);
    }

    // ---- epilogue
    float4 oa, ob;
    float4* orow0 = reinterpret_cast<float4*>(out) + (size_t)row0 * (DIM / 4);
    oa.x = fmaxf(0.f, z0[0] - tau0);
    oa.y = fmaxf(0.f, z0[1] - tau0);
    oa.z = fmaxf(0.f, z0[2] - tau0);
    oa.w = fmaxf(0.f, z0[3] - tau0);
    ob.x = fmaxf(0.f, z0[4] - tau0);
    ob.y = fmaxf(0.f, z0[5] - tau0);
    ob.z = fmaxf(0.f, z0[6] - tau0);
    ob.w = fmaxf(0.f, z0[7] - tau0);
    orow0[lane]        = oa;
    orow0[lane + WAVE] = ob;

    float4* orow1 = orow0 + (DIM / 4);
    oa.x = fmaxf(0.f, z1[0] - tau1);
    oa.y = fmaxf(0.f, z1[1] - tau1);
    oa.z = fmaxf(0.f, z1[2] - tau1);
    oa.w = fmaxf(0.f, z1[3] - tau1);
    ob.x = fmaxf(0.f, z1[4] - tau1);
    ob.y = fmaxf(0.f, z1[5] - tau1);
    ob.z = fmaxf(0.f, z1[6] - tau1);
    ob.w = fmaxf(0.f, z1[7] - tau1);
    orow1[lane]        = oa;
    orow1[lane + WAVE] = ob;
}

extern "C" void kernel_launch(void* const* d_in, const int* in_sizes, int n_in,
                              void* d_out, int out_size, void* d_ws, size_t ws_size,
                              hipStream_t stream) {
    const float* x = (const float*)d_in[0];
    float* out     = (float*)d_out;
    const int batch = in_sizes[0] / DIM;  // 65536
    const int grid  = (batch + ROWS_PER_BLOCK - 1) / ROWS_PER_BLOCK;  // 8192
    sparsemax_kernel<<<grid, BLOCK, 0, stream>>>(x, out, batch);
}